// Round 11
// baseline (140.662 us; speedup 1.0000x reference)
//
#include <hip/hip_runtime.h>

// Problem: attention, q,k,v [B=4, N=2048, H=8, D=64] fp32 -> out same.
#define B 4
#define N 2048
#define H 8
#define D 64
#define HD 512              // row stride (elements) for fixed (b,h)
#define QT 128              // q rows per block (4 q-groups x 32, x 2 key-halves)
#define KT 64               // keys per tile
#define NT2 16              // tiles per key-half (split-K)
#define PLS 72              // prep-kernel LDS pad stride
#define HEADE 131072        // N*D halves per (b,h)

typedef _Float16 half8 __attribute__((ext_vector_type(8)));
typedef float float4_ __attribute__((ext_vector_type(4)));
typedef float float16_ __attribute__((ext_vector_type(16)));

#define MFMA32(a, b, c) __builtin_amdgcn_mfma_f32_32x32x16_f16((a), (b), (c), 0, 0, 0)

// ---------------- prepass: K,V -> FRAGMENT-MAJOR f16 layouts ----------------
// Kt2: per head, per tile tt (64 keys): 16 chunks c = kb*8 + (2ks+hi); chunk = 32 lanes x 8
// halves where lane ln holds K[tt*64+kb*32+ln][8*(2ks+hi) .. +8]. A-frag load for (kb,ks)
// = two contiguous 512B runs (hi 0/1). addr = ((tt*16+c)*32+ln)*8.
// Vt2: per head, per tile: 8 chunks ch (tau'd key positions ch*8..+8), chunk = 64 d x 8
// halves: addr = ((tt*8+ch)*512) + d*8. B-frag (ks,hi) = chunk 2ks+hi, d=ln / 32+ln.
// tau (swap key bits 2<->3, verified R2) is baked into the w0/w1 construction below.
__global__ void prep2_kernel(const float* __restrict__ K, const float* __restrict__ V,
                             _Float16* __restrict__ Kt2, _Float16* __restrict__ Vt2) {
    __shared__ _Float16 tile[64][PLS];
    const int t = threadIdx.x;
    if (blockIdx.x < 1024) {
        // K part: block = (b,h,tt)
        const int bid = blockIdx.x;
        const int tt = bid & 31, h = (bid >> 5) & 7, b = bid >> 8;
        const size_t src = (size_t)b * N * HD + (size_t)h * D;
        const size_t dst = (size_t)(b * H + h) * HEADE;
        const int c  = t >> 4;             // chunk 0..15 = kb*8 + ch
        const int lp = (t & 15) * 2;       // lane pair
        #pragma unroll
        for (int i = 0; i < 2; ++i) {
            const int l = lp + i;
            const int row = tt * 64 + (c >> 3) * 32 + l;
            const float* sp = K + src + (size_t)row * HD + (c & 7) * 8;
            float4_ a0 = *(const float4_*)sp, a1 = *(const float4_*)(sp + 4);
            half8 f;
            #pragma unroll
            for (int j = 0; j < 4; ++j) { f[j] = (_Float16)a0[j]; f[4 + j] = (_Float16)a1[j]; }
            *(half8*)(Kt2 + dst + ((size_t)(tt * 16 + c) * 32 + l) * 8) = f;
        }
    } else {
        // V part: block = (b,h,nt); LDS transpose then tau'd chunk store
        const int bid = blockIdx.x - 1024;
        const int nt = bid & 31, h = (bid >> 5) & 7, b = bid >> 8;
        {
            const int i = t >> 2, c0 = (t & 3) * 16;
            const float* vp = V + (size_t)b * N * HD + (size_t)(nt * 64 + i) * HD + h * D + c0;
            #pragma unroll
            for (int j = 0; j < 4; ++j) {
                float4_ a = *(const float4_*)(vp + j * 4);
                #pragma unroll
                for (int cc = 0; cc < 4; ++cc) tile[i][c0 + j * 4 + cc] = (_Float16)a[cc];
            }
        }
        __syncthreads();
        {
            const int d = t >> 2, n0 = (t & 3) * 16;
            // tau within the 16-run: chunk c0 holds keys n0+{0,1,2,3,8,9,10,11};
            //                        chunk c0+1 holds keys n0+{4,5,6,7,12,13,14,15}.
            half8 w0, w1;
            #pragma unroll
            for (int j = 0; j < 4; ++j) {
                w0[j]     = tile[n0 + j][d];
                w0[4 + j] = tile[n0 + 8 + j][d];
                w1[j]     = tile[n0 + 4 + j][d];
                w1[4 + j] = tile[n0 + 12 + j][d];
            }
            const int c0 = (t & 3) * 2;
            _Float16* op = Vt2 + (size_t)(b * H + h) * HEADE
                               + (size_t)(nt * 8 + c0) * 512 + d * 8;
            *(half8*)op = w0;
            *(half8*)(op + 512) = w1;
        }
    }
}

// ---- per-phase compute. NO LDS, NO barriers in the main loop: A/B fragments load
// ---- directly from the fragment-major global layouts (coalesced 512B runs, L2-resident).
// ---- All cross-statement values are NAMED scalars (rule 20). V loads are split into
// ---- two half-phase windows to cap register pressure (<=128 for 2 blocks/CU). ----
#define DO_S_HALF(TT, KB, PA, PB)                                              \
    {                                                                          \
        const _Float16* kp_ = Kb2 + ((size_t)((TT) * 16 + (KB) * 8 + hi) * 32 + ln) * 8; \
        half8 a0_ = *(const half8*)(kp_);                                      \
        half8 a1_ = *(const half8*)(kp_ + 512);                                \
        half8 a2_ = *(const half8*)(kp_ + 1024);                               \
        half8 a3_ = *(const half8*)(kp_ + 1536);                               \
        float16_ s_ = {};                                                      \
        __builtin_amdgcn_s_setprio(1);                                         \
        s_ = MFMA32(a0_, qf[0], s_);                                           \
        s_ = MFMA32(a1_, qf[1], s_);                                           \
        s_ = MFMA32(a2_, qf[2], s_);                                           \
        s_ = MFMA32(a3_, qf[3], s_);                                           \
        __builtin_amdgcn_s_setprio(0);                                         \
        half8 f0_, f1_;                                                        \
        _Pragma("unroll")                                                      \
        for (int j = 0; j < 8; ++j) {                                          \
            float pa_ = __builtin_amdgcn_exp2f(s_[j]);                         \
            float pb_ = __builtin_amdgcn_exp2f(s_[8 + j]);                     \
            ls0 += pa_; ls1 += pb_;                                            \
            f0_[j] = (_Float16)pa_;                                            \
            f1_[j] = (_Float16)pb_;                                            \
        }                                                                      \
        PA = f0_; PB = f1_;                                                    \
    }

#define LOAD_V01(TT)                                                           \
    {                                                                          \
        const _Float16* vp_ = Vb2 + (size_t)((TT) * 8 + hi) * 512 + ln * 8;    \
        v00 = *(const half8*)(vp_);                                            \
        v01 = *(const half8*)(vp_ + 256);                                      \
        v10 = *(const half8*)(vp_ + 1024);                                     \
        v11 = *(const half8*)(vp_ + 1280);                                     \
    }
#define LOAD_V23(TT)                                                           \
    {                                                                          \
        const _Float16* vp_ = Vb2 + (size_t)((TT) * 8 + hi) * 512 + ln * 8;    \
        v20 = *(const half8*)(vp_ + 2048);                                     \
        v21 = *(const half8*)(vp_ + 2304);                                     \
        v30 = *(const half8*)(vp_ + 3072);                                     \
        v31 = *(const half8*)(vp_ + 3328);                                     \
    }
#define PV01(P0, P1)                                                           \
    __builtin_amdgcn_s_setprio(1);                                             \
    o0 = MFMA32(P0, v00, o0); o1 = MFMA32(P0, v01, o1);                        \
    o0 = MFMA32(P1, v10, o0); o1 = MFMA32(P1, v11, o1);                        \
    __builtin_amdgcn_s_setprio(0);
#define PV23(P2, P3)                                                           \
    __builtin_amdgcn_s_setprio(1);                                             \
    o0 = MFMA32(P2, v20, o0); o1 = MFMA32(P2, v21, o1);                        \
    o0 = MFMA32(P3, v30, o0); o1 = MFMA32(P3, v31, o1);                        \
    __builtin_amdgcn_s_setprio(0);

// Phase T (T>=1): interleave { V(T-1) half-load, S(T) half, PV(T-1) half } x2.
// V loads issue before the S half that hides their L2 latency.
#define PHASE_PV(T, C0, C1, C2, C3, Pp0, Pp1, Pp2, Pp3)                        \
    {                                                                          \
        LOAD_V01(kh16 + (T) - 1)                                               \
        DO_S_HALF(kh16 + (T), 0, C0, C1)                                       \
        PV01(Pp0, Pp1)                                                         \
        LOAD_V23(kh16 + (T) - 1)                                               \
        DO_S_HALF(kh16 + (T), 1, C2, C3)                                       \
        PV23(Pp2, Pp3)                                                         \
    }

// ---- main: split-K, 8 waves (4 qg x 2 kh), fully barrier-free streaming ----
__global__ __launch_bounds__(512, 2)
void fattn15_kernel(const float* __restrict__ Q, const _Float16* __restrict__ Kt2,
                    const _Float16* __restrict__ Vt2, float* __restrict__ Out)
{
    __shared__ float cbuf[8448];               // combine scratch only (33792 B)

    const int tid  = threadIdx.x;
    const int wave = tid >> 6;
    const int lane = tid & 63;
    const int ln   = lane & 31;
    const int hi   = lane >> 5;
    const int qg   = wave & 3;      // q-group: 32 q-rows
    const int kh   = wave >> 2;     // key-half: tiles [kh*16, kh*16+16)
    const int kh16 = kh * 16;

    const int h = blockIdx.y;
    const int b = blockIdx.z;
    const int q_base = blockIdx.x * QT + qg * 32;

    const size_t bh_q = (size_t)b * N * HD + (size_t)h * D;
    const size_t headb = (size_t)(b * H + h) * HEADE;
    const _Float16* Kb2 = Kt2 + headb;
    const _Float16* Vb2 = Vt2 + headb;

    // Q rows in registers as S^T B-frags: qf[ks][j] = Q[q_base+ln][ks*16+hi*8+j]*SC
    const float SC = 0.125f * 1.4426950408889634f;
    half8 qf[4];
    {
        const float* qp = Q + bh_q + (size_t)(q_base + ln) * HD + hi * 8;
        #pragma unroll
        for (int ks = 0; ks < 4; ++ks) {
            float4_ a0 = *(const float4_*)(qp + ks * 16);
            float4_ a1 = *(const float4_*)(qp + ks * 16 + 4);
            half8 f;
            #pragma unroll
            for (int j = 0; j < 4; ++j) { f[j] = (_Float16)(a0[j] * SC); f[4 + j] = (_Float16)(a1[j] * SC); }
            qf[ks] = f;
        }
    }

    float16_ o0 = {}, o1 = {};
    float ls0 = 0.f, ls1 = 0.f;
    half8 pa0, pa1, pa2, pa3;       // P fragments, phase parity A
    half8 pb0, pb1, pb2, pb3;       // P fragments, phase parity B
    half8 v00, v01, v10, v11, v20, v21, v30, v31;   // V fragments (half-phase windows)

    // phase 0: S(0) only
    DO_S_HALF(kh16, 0, pa0, pa1)
    DO_S_HALF(kh16, 1, pa2, pa3)
    // phases 1..14: PV(t-1) interleaved with S(t), alternating parities
    for (int t = 1; t < NT2 - 1; t += 2) {
        PHASE_PV(t,     pb0, pb1, pb2, pb3, pa0, pa1, pa2, pa3)
        PHASE_PV(t + 1, pa0, pa1, pa2, pa3, pb0, pb1, pb2, pb3)
    }
    // phase 15: S(15)->pb, PV(14) from pa
    PHASE_PV(NT2 - 1, pb0, pb1, pb2, pb3, pa0, pa1, pa2, pa3)
    // final: PV(15) from pb
    LOAD_V01(kh16 + NT2 - 1)
    PV01(pb0, pb1)
    LOAD_V23(kh16 + NT2 - 1)
    PV23(pb2, pb3)
    float lsum = ls0 + ls1;

    // ---- combine epilogue: sum the two key-half partials through LDS ----
    __syncthreads();                           // first barrier in the kernel
    float* cb = cbuf;                          // [qg][dh][r][lane] = 8192 floats
    float* ls = cbuf + 8192;                   // [qg][lane] = 256 floats
    if (kh == 1) {
        #pragma unroll
        for (int r = 0; r < 16; ++r) {
            cb[((qg * 2 + 0) * 16 + r) * 64 + lane] = o0[r];
            cb[((qg * 2 + 1) * 16 + r) * 64 + lane] = o1[r];
        }
        ls[qg * 64 + lane] = lsum;
    }
    __syncthreads();
    if (kh == 0) {
        #pragma unroll
        for (int r = 0; r < 16; ++r) {
            o0[r] += cb[((qg * 2 + 0) * 16 + r) * 64 + lane];
            o1[r] += cb[((qg * 2 + 1) * 16 + r) * 64 + lane];
        }
        lsum += ls[qg * 64 + lane];
        // finalize: per-lane row sums (q = ln, split by hi); combine halves, store
        float v = lsum;
        v += __shfl_xor(v, 32, 64);
        const float inv = 1.0f / v;
        #pragma unroll
        for (int r = 0; r < 16; ++r) {
            const int rl = (r & 3) + 8 * (r >> 2) + 4 * hi;
            const float linv = __shfl(inv, rl, 64);
            const size_t ro = bh_q + (size_t)(q_base + rl) * HD;
            Out[ro + ln]      = o0[r] * linv;
            Out[ro + 32 + ln] = o1[r] * linv;
        }
    }
}

// ---------------- fallback (round-1 verified kernel) if ws too small ----------------
__global__ __launch_bounds__(256, 2)
void fattn_fb_kernel(const float* __restrict__ Q, const float* __restrict__ K,
                     const float* __restrict__ V, float* __restrict__ Out)
{
    __shared__ __align__(16) _Float16 Ks[KT][PLS];
    __shared__ __align__(16) _Float16 Vts[D][PLS];
    __shared__ __align__(16) _Float16 Pwf[4][16][PLS];
    const int tid = threadIdx.x, wave = tid >> 6, lane = tid & 63;
    const int m = lane & 15, quad = lane >> 4;
    const int q_base = blockIdx.x * 64;
    const size_t bh_off = ((size_t)blockIdx.z * N * H + (size_t)blockIdx.y) * D;
    const float SCALE = 0.125f;
    const int qrow = q_base + wave * 16 + m;
    const float* qp = Q + bh_off + (size_t)qrow * HD + quad * 8;
    half8 qf0, qf1;
    #pragma unroll
    for (int j = 0; j < 8; ++j) qf0[j] = (_Float16)(qp[j] * SCALE);
    #pragma unroll
    for (int j = 0; j < 8; ++j) qf1[j] = (_Float16)(qp[32 + j] * SCALE);
    float4_ o[4] = {};
    float mi[4], li[4];
    #pragma unroll
    for (int r = 0; r < 4; ++r) { mi[r] = -1e30f; li[r] = 0.0f; }
    for (int kt = 0; kt < N; kt += KT) {
        __syncthreads();
        {
            const int key = tid >> 2, c0 = (tid & 3) * 16;
            const float* kp = K + bh_off + (size_t)(kt + key) * HD + c0;
            half8 lo, hi;
            #pragma unroll
            for (int j = 0; j < 8; ++j) lo[j] = (_Float16)kp[j];
            #pragma unroll
            for (int j = 0; j < 8; ++j) hi[j] = (_Float16)kp[8 + j];
            *(half8*)&Ks[key][c0] = lo;
            *(half8*)&Ks[key][c0 + 8] = hi;
        }
        {
            const int c0 = (tid & 15) * 4, k0 = (tid >> 4) * 4;
            const float* vp = V + bh_off + (size_t)(kt + k0) * HD + c0;
            #pragma unroll
            for (int c = 0; c < 4; ++c)
                #pragma unroll
                for (int i = 0; i < 4; ++i)
                    Vts[c0 + c][k0 + i] = (_Float16)vp[i * HD + c];
        }
        __syncthreads();
        float4_ s[4];
        #pragma unroll
        for (int blk = 0; blk < 4; ++blk) {
            const int key = blk * 16 + m;
            half8 kf0 = *(const half8*)&Ks[key][quad * 8];
            half8 kf1 = *(const half8*)&Ks[key][32 + quad * 8];
            float4_ acc = {};
            acc = __builtin_amdgcn_mfma_f32_16x16x32_f16(qf0, kf0, acc, 0, 0, 0);
            acc = __builtin_amdgcn_mfma_f32_16x16x32_f16(qf1, kf1, acc, 0, 0, 0);
            s[blk] = acc;
        }
        float alpha[4];
        #pragma unroll
        for (int r = 0; r < 4; ++r) {
            float v0 = fmaxf(fmaxf(s[0][r], s[1][r]), fmaxf(s[2][r], s[3][r]));
            #pragma unroll
            for (int mask = 1; mask < 16; mask <<= 1) v0 = fmaxf(v0, __shfl_xor(v0, mask, 64));
            float mn = fmaxf(mi[r], v0);
            alpha[r] = __expf(mi[r] - mn);
            mi[r] = mn;
        }
        #pragma unroll
        for (int blk = 0; blk < 4; ++blk)
            #pragma unroll
            for (int r = 0; r < 4; ++r) s[blk][r] = __expf(s[blk][r] - mi[r]);
        #pragma unroll
        for (int r = 0; r < 4; ++r) {
            float tt = s[0][r] + s[1][r] + s[2][r] + s[3][r];
            #pragma unroll
            for (int mask = 1; mask < 16; mask <<= 1) tt += __shfl_xor(tt, mask, 64);
            li[r] = li[r] * alpha[r] + tt;
        }
        #pragma unroll
        for (int d = 0; d < 4; ++d)
            #pragma unroll
            for (int r = 0; r < 4; ++r) o[d][r] *= alpha[r];
        #pragma unroll
        for (int blk = 0; blk < 4; ++blk)
            #pragma unroll
            for (int r = 0; r < 4; ++r)
                Pwf[wave][quad * 4 + r][blk * 16 + m] = (_Float16)s[blk][r];
        #pragma unroll
        for (int ks = 0; ks < 2; ++ks) {
            half8 af = *(const half8*)&Pwf[wave][m][ks * 32 + quad * 8];
            #pragma unroll
            for (int d = 0; d < 4; ++d) {
                half8 bf = *(const half8*)&Vts[d * 16 + m][ks * 32 + quad * 8];
                o[d] = __builtin_amdgcn_mfma_f32_16x16x32_f16(af, bf, o[d], 0, 0, 0);
            }
        }
    }
    #pragma unroll
    for (int d = 0; d < 4; ++d)
        #pragma unroll
        for (int r = 0; r < 4; ++r) {
            const int row = q_base + wave * 16 + quad * 4 + r;
            Out[bh_off + (size_t)row * HD + d * 16 + m] = o[d][r] / li[r];
        }
}

extern "C" void kernel_launch(void* const* d_in, const int* in_sizes, int n_in,
                              void* d_out, int out_size, void* d_ws, size_t ws_size,
                              hipStream_t stream) {
    const float* q = (const float*)d_in[0];
    const float* k = (const float*)d_in[1];
    const float* v = (const float*)d_in[2];
    float* out = (float*)d_out;

    const size_t nelem = (size_t)B * N * H * D;           // 4194304
    const size_t need = 2 * nelem * sizeof(_Float16);     // Kt2 + Vt2

    if (ws_size >= need) {
        _Float16* Kt2 = (_Float16*)d_ws;
        _Float16* Vt2 = Kt2 + nelem;
        prep2_kernel<<<dim3(2048), 256, 0, stream>>>(k, v, Kt2, Vt2);
        fattn15_kernel<<<dim3(N / QT, H, B), 512, 0, stream>>>(q, Kt2, Vt2, out);
    } else {
        fattn_fb_kernel<<<dim3(N / 64, H, B), 256, 0, stream>>>(q, k, v, out);
    }
}

// Round 12
// 139.366 us; speedup vs baseline: 1.0093x; 1.0093x over previous
//
#include <hip/hip_runtime.h>

// Problem: attention, q,k,v [B=4, N=2048, H=8, D=64] fp32 -> out same.
#define B 4
#define N 2048
#define H 8
#define D 64
#define HD 512              // row stride (elements) for fixed (b,h)
#define QT 128              // q rows per block (4 q-groups x 32, x 2 key-halves)
#define KT 64               // keys per tile
#define NT2 16              // tiles per key-half (split-K)
#define PLS 72              // prep-kernel LDS pad stride

typedef _Float16 half8 __attribute__((ext_vector_type(8)));
typedef float float4_ __attribute__((ext_vector_type(4)));
typedef float float16_ __attribute__((ext_vector_type(16)));

#define MFMA32(a, b, c) __builtin_amdgcn_mfma_f32_32x32x16_f16((a), (b), (c), 0, 0, 0)

// ---------------- fused prepass: K f32->f16 same layout; V -> Vt [b,h,d,n'] f16 ----------------
// Vt key axis is tau-permuted: position p holds original key tau(p), tau = swap bits 2<->3.
// tau makes the 32x32 MFMA S-tile D-rows line up with the PV A-operand k-slots per lane,
// so P never needs a cross-lane exchange (verified in R2).
__global__ void prep_kernel(const float* __restrict__ K, const float* __restrict__ V,
                            _Float16* __restrict__ Kf, _Float16* __restrict__ Vtr) {
    __shared__ _Float16 tile[64][PLS];
    const int t = threadIdx.x;
    if (blockIdx.x < 2048) {
        const size_t i = (size_t)blockIdx.x * 256 + t;
        const float4_* p = (const float4_*)(K + i * 8);
        float4_ a = p[0], b = p[1];
        half8 hh;
        #pragma unroll
        for (int j = 0; j < 4; ++j) { hh[j] = (_Float16)a[j]; hh[4 + j] = (_Float16)b[j]; }
        *(half8*)(Kf + i * 8) = hh;
    } else {
        const int bid = blockIdx.x - 2048;
        const int nt = bid & 31, h = (bid >> 5) & 7, b = bid >> 8;
        {
            const int i = t >> 2, c0 = (t & 3) * 16;
            const float* vp = V + (size_t)b * N * HD + (size_t)(nt * 64 + i) * HD + h * D + c0;
            #pragma unroll
            for (int j = 0; j < 4; ++j) {
                float4_ a = *(const float4_*)(vp + j * 4);
                #pragma unroll
                for (int c = 0; c < 4; ++c) tile[i][c0 + j * 4 + c] = (_Float16)a[c];
            }
        }
        __syncthreads();
        {
            const int d = t >> 2, n0 = (t & 3) * 16;
            // tau within the 16-run: positions n0+0..7 hold keys n0+{0,1,2,3,8,9,10,11};
            //                        positions n0+8..15 hold keys n0+{4,5,6,7,12,13,14,15}.
            half8 w0, w1;
            #pragma unroll
            for (int j = 0; j < 4; ++j) {
                w0[j]     = tile[n0 + j][d];
                w0[4 + j] = tile[n0 + 8 + j][d];
                w1[j]     = tile[n0 + 4 + j][d];
                w1[4 + j] = tile[n0 + 12 + j][d];
            }
            _Float16* op = Vtr + ((size_t)(b * H + h) * D + d) * N + nt * 64 + n0;
            *(half8*)op = w0;
            *(half8*)(op + 8) = w1;
        }
    }
}

// ------- async staging (chunk-swizzled, group-split); wg in [0,4) covers 16 rows each -------
__device__ __forceinline__ void stage_k(const _Float16* __restrict__ Kbh, int keybase,
                                        _Float16* kb, int wg, int lane) {
    const int rsub = lane >> 3, slot = lane & 7;
    #pragma unroll
    for (int i = 0; i < 2; ++i) {
        const int row = wg * 16 + i * 8 + rsub;
        const int c = slot ^ (row & 7);
        __builtin_amdgcn_global_load_lds(
            (const __attribute__((address_space(1))) void*)(Kbh + (size_t)(keybase + row) * HD + c * 8),
            (__attribute__((address_space(3))) void*)(kb + (wg * 16 + i * 8) * 64), 16, 0, 0);
    }
}
__device__ __forceinline__ void stage_v(const _Float16* __restrict__ Vbh, int keybase,
                                        _Float16* vb, int wg, int lane) {
    const int rsub = lane >> 3, slot = lane & 7;
    #pragma unroll
    for (int i = 0; i < 2; ++i) {
        const int row = wg * 16 + i * 8 + rsub;      // d row
        const int c = slot ^ (row & 7);
        __builtin_amdgcn_global_load_lds(
            (const __attribute__((address_space(1))) void*)(Vbh + (size_t)row * N + keybase + c * 8),
            (__attribute__((address_space(3))) void*)(vb + (wg * 16 + i * 8) * 64), 16, 0, 0);
    }
}

// ------- main: R6 base (split-K, 8 waves, dbuf, counted vmcnt) + lsum-via-ones-MFMA -------
// lsum = P . 1 computed on the MATRIX pipe (lsacc = MFMA32(pf, ones, lsacc)): removes the
// 32 serially-chained VALU fadds per tile from the S->PV spine; +4 MFMAs/tile into the
// 72%-idle matrix pipe. lsacc D-layout duplicates row-sums across columns, so the epilogue
// publishes them from lane ln==0 of each hi-half with STATIC reg indexing (rule 20).
// (512,2): lsacc+ones push the body past the 64-reg cap of (512,4); occupancy stays
// 2 blocks/CU (LDS-bound at 64 KB).
__global__ __launch_bounds__(512, 2)
void fattn16_kernel(const float* __restrict__ Q, const _Float16* __restrict__ Kf,
                    const _Float16* __restrict__ Vt, float* __restrict__ Out)
{
    // 64 KB: 2 streams x 2 K-buffers + 2 streams x 2 V-buffers (4096 halves each).
    // Epilogue reuses it as float scratch (33.8 KB needed).
    static __shared__ __align__(16) _Float16 smem[32768];

    const int tid  = threadIdx.x;
    const int wave = tid >> 6;
    const int lane = tid & 63;
    const int ln   = lane & 31;
    const int hi   = lane >> 5;
    const int qg   = wave & 3;      // q-group: 32 q-rows
    const int kh   = wave >> 2;     // key-half: tiles [kh*16, kh*16+16)

    const int h = blockIdx.y;
    const int b = blockIdx.z;
    const int q_base = blockIdx.x * QT + qg * 32;

    const size_t bh_q = (size_t)b * N * HD + (size_t)h * D;
    const _Float16* Kbh = Kf + bh_q;
    const _Float16* Vbh = Vt + (size_t)(b * H + h) * D * N;

    _Float16* Kbuf = smem + kh * 8192;           // stream-local 2 x 4096
    _Float16* Vbuf = smem + 16384 + kh * 8192;

    // Q rows in registers as S^T B-frags: qf[ks][j] = Q[q_base+ln][ks*16+hi*8+j]*SC
    const float SC = 0.125f * 1.4426950408889634f;
    half8 qf[4];
    {
        const float* qp = Q + bh_q + (size_t)(q_base + ln) * HD + hi * 8;
        #pragma unroll
        for (int ks = 0; ks < 4; ++ks) {
            float4_ a0 = *(const float4_*)(qp + ks * 16);
            float4_ a1 = *(const float4_*)(qp + ks * 16 + 4);
            half8 f;
            #pragma unroll
            for (int j = 0; j < 4; ++j) { f[j] = (_Float16)(a0[j] * SC); f[4 + j] = (_Float16)(a1[j] * SC); }
            qf[ks] = f;
        }
    }

    float16_ o0 = {}, o1 = {}, lsacc = {};
    half8 ones;
    #pragma unroll
    for (int j = 0; j < 8; ++j) ones[j] = (_Float16)1.0f;

    // prologue: stage this stream's tiles 0 and 1 (4 vmem ops per tile per wave)
    const int tbase = kh * NT2 * KT;
    stage_k(Kbh, tbase, Kbuf, qg, lane);              stage_v(Vbh, tbase, Vbuf, qg, lane);
    stage_k(Kbh, tbase + KT, Kbuf + 4096, qg, lane);  stage_v(Vbh, tbase + KT, Vbuf + 4096, qg, lane);

    for (int t = 0; t < NT2; ++t) {
        // counted retire: tile t's 4 loads are the oldest; tile t+1's 4 stay in flight.
        if (t < NT2 - 1) asm volatile("s_waitcnt vmcnt(4)" ::: "memory");
        else             asm volatile("s_waitcnt vmcnt(0)" ::: "memory");
        __builtin_amdgcn_s_barrier();          // all waves' tile-t staging now visible
        __builtin_amdgcn_sched_barrier(0);

        const _Float16* kc = Kbuf + (t & 1) * 4096;
        const _Float16* vc = Vbuf + (t & 1) * 4096;

        // ---- S(t): S^T = K (Q*sc)^T, 32x32x16; exp2; pack (no VALU lsum) ----
        half8 pf[4];
        #pragma unroll
        for (int kb = 0; kb < 2; ++kb) {
            float16_ s = {};
            __builtin_amdgcn_s_setprio(1);
            #pragma unroll
            for (int ks = 0; ks < 4; ++ks) {
                const int csw = ((2 * ks + hi) ^ (ln & 7)) * 8;
                half8 a = *(const half8*)(kc + (kb * 32 + ln) * 64 + csw);
                s = MFMA32(a, qf[ks], s);
            }
            __builtin_amdgcn_s_setprio(0);
            half8 f0, f1;
            #pragma unroll
            for (int j = 0; j < 8; ++j) {
                f0[j] = (_Float16)__builtin_amdgcn_exp2f(s[j]);
                f1[j] = (_Float16)__builtin_amdgcn_exp2f(s[8 + j]);
            }
            pf[2 * kb]     = f0;
            pf[2 * kb + 1] = f1;
        }

        // ---- PV(t) + row-sum MFMA stream (lsacc) ----
        __builtin_amdgcn_s_setprio(1);
        #pragma unroll
        for (int ks = 0; ks < 4; ++ks) {
            const int csw = ((2 * ks + hi) ^ (ln & 7)) * 8;
            half8 b0 = *(const half8*)(vc + ln * 64 + csw);
            half8 b1 = *(const half8*)(vc + (32 + ln) * 64 + csw);
            o0 = MFMA32(pf[ks], b0, o0);
            o1 = MFMA32(pf[ks], b1, o1);
            lsacc = MFMA32(pf[ks], ones, lsacc);
        }
        __builtin_amdgcn_s_setprio(0);

        // end-of-phase: buf slot t&1 fully consumed by all waves -> overwrite with tile t+2
        if (t + 2 < NT2) {
            __builtin_amdgcn_s_barrier();
            __builtin_amdgcn_sched_barrier(0);
            stage_k(Kbh, tbase + (t + 2) * KT, Kbuf + (t & 1) * 4096, qg, lane);
            stage_v(Vbh, tbase + (t + 2) * KT, Vbuf + (t & 1) * 4096, qg, lane);
        }
    }

    // ---- combine epilogue: o-partials via LDS; row-sums from lsacc (dup'd across cols) ----
    __syncthreads();                           // all waves done reading K/V LDS
    float* cb  = (float*)smem;                 // [qg][dh][r][lane] = 8192 floats (32 KB)
    float* lsW = cb + 8192;                    // [kh][qg][32 q] = 256 floats
    if (kh == 1) {
        #pragma unroll
        for (int r = 0; r < 16; ++r) {
            cb[((qg * 2 + 0) * 16 + r) * 64 + lane] = o0[r];
            cb[((qg * 2 + 1) * 16 + r) * 64 + lane] = o1[r];
        }
    }
    if (ln == 0) {                             // lanes 0 (hi=0) and 32 (hi=1): publish 16 each
        #pragma unroll
        for (int r = 0; r < 16; ++r) {
            const int rl = (r & 3) + 8 * (r >> 2) + 4 * hi;
            lsW[(kh * 4 + qg) * 32 + rl] = lsacc[r];
        }
    }
    __syncthreads();
    if (kh == 0) {
        #pragma unroll
        for (int r = 0; r < 16; ++r) {
            o0[r] += cb[((qg * 2 + 0) * 16 + r) * 64 + lane];
            o1[r] += cb[((qg * 2 + 1) * 16 + r) * 64 + lane];
        }
        #pragma unroll
        for (int r = 0; r < 16; ++r) {
            const int rl = (r & 3) + 8 * (r >> 2) + 4 * hi;
            const float tot = lsW[(0 * 4 + qg) * 32 + rl] + lsW[(1 * 4 + qg) * 32 + rl];
            const float linv = 1.0f / tot;
            const size_t ro = bh_q + (size_t)(q_base + rl) * HD;
            Out[ro + ln]      = o0[r] * linv;
            Out[ro + 32 + ln] = o1[r] * linv;
        }
    }
}

// ---------------- fallback (round-1 verified kernel) if ws too small ----------------
__global__ __launch_bounds__(256, 2)
void fattn_fb_kernel(const float* __restrict__ Q, const float* __restrict__ K,
                     const float* __restrict__ V, float* __restrict__ Out)
{
    __shared__ __align__(16) _Float16 Ks[KT][PLS];
    __shared__ __align__(16) _Float16 Vts[D][PLS];
    __shared__ __align__(16) _Float16 Pwf[4][16][PLS];
    const int tid = threadIdx.x, wave = tid >> 6, lane = tid & 63;
    const int m = lane & 15, quad = lane >> 4;
    const int q_base = blockIdx.x * 64;
    const size_t bh_off = ((size_t)blockIdx.z * N * H + (size_t)blockIdx.y) * D;
    const float SCALE = 0.125f;
    const int qrow = q_base + wave * 16 + m;
    const float* qp = Q + bh_off + (size_t)qrow * HD + quad * 8;
    half8 qf0, qf1;
    #pragma unroll
    for (int j = 0; j < 8; ++j) qf0[j] = (_Float16)(qp[j] * SCALE);
    #pragma unroll
    for (int j = 0; j < 8; ++j) qf1[j] = (_Float16)(qp[32 + j] * SCALE);
    float4_ o[4] = {};
    float mi[4], li[4];
    #pragma unroll
    for (int r = 0; r < 4; ++r) { mi[r] = -1e30f; li[r] = 0.0f; }
    for (int kt = 0; kt < N; kt += KT) {
        __syncthreads();
        {
            const int key = tid >> 2, c0 = (tid & 3) * 16;
            const float* kp = K + bh_off + (size_t)(kt + key) * HD + c0;
            half8 lo, hi;
            #pragma unroll
            for (int j = 0; j < 8; ++j) lo[j] = (_Float16)kp[j];
            #pragma unroll
            for (int j = 0; j < 8; ++j) hi[j] = (_Float16)kp[8 + j];
            *(half8*)&Ks[key][c0] = lo;
            *(half8*)&Ks[key][c0 + 8] = hi;
        }
        {
            const int c0 = (tid & 15) * 4, k0 = (tid >> 4) * 4;
            const float* vp = V + bh_off + (size_t)(kt + k0) * HD + c0;
            #pragma unroll
            for (int c = 0; c < 4; ++c)
                #pragma unroll
                for (int i = 0; i < 4; ++i)
                    Vts[c0 + c][k0 + i] = (_Float16)vp[i * HD + c];
        }
        __syncthreads();
        float4_ s[4];
        #pragma unroll
        for (int blk = 0; blk < 4; ++blk) {
            const int key = blk * 16 + m;
            half8 kf0 = *(const half8*)&Ks[key][quad * 8];
            half8 kf1 = *(const half8*)&Ks[key][32 + quad * 8];
            float4_ acc = {};
            acc = __builtin_amdgcn_mfma_f32_16x16x32_f16(qf0, kf0, acc, 0, 0, 0);
            acc = __builtin_amdgcn_mfma_f32_16x16x32_f16(qf1, kf1, acc, 0, 0, 0);
            s[blk] = acc;
        }
        float alpha[4];
        #pragma unroll
        for (int r = 0; r < 4; ++r) {
            float v0 = fmaxf(fmaxf(s[0][r], s[1][r]), fmaxf(s[2][r], s[3][r]));
            #pragma unroll
            for (int mask = 1; mask < 16; mask <<= 1) v0 = fmaxf(v0, __shfl_xor(v0, mask, 64));
            float mn = fmaxf(mi[r], v0);
            alpha[r] = __expf(mi[r] - mn);
            mi[r] = mn;
        }
        #pragma unroll
        for (int blk = 0; blk < 4; ++blk)
            #pragma unroll
            for (int r = 0; r < 4; ++r) s[blk][r] = __expf(s[blk][r] - mi[r]);
        #pragma unroll
        for (int r = 0; r < 4; ++r) {
            float tt = s[0][r] + s[1][r] + s[2][r] + s[3][r];
            #pragma unroll
            for (int mask = 1; mask < 16; mask <<= 1) tt += __shfl_xor(tt, mask, 64);
            li[r] = li[r] * alpha[r] + tt;
        }
        #pragma unroll
        for (int d = 0; d < 4; ++d)
            #pragma unroll
            for (int r = 0; r < 4; ++r) o[d][r] *= alpha[r];
        #pragma unroll
        for (int blk = 0; blk < 4; ++blk)
            #pragma unroll
            for (int r = 0; r < 4; ++r)
                Pwf[wave][quad * 4 + r][blk * 16 + m] = (_Float16)s[blk][r];
        #pragma unroll
        for (int ks = 0; ks < 2; ++ks) {
            half8 af = *(const half8*)&Pwf[wave][m][ks * 32 + quad * 8];
            #pragma unroll
            for (int d = 0; d < 4; ++d) {
                half8 bf = *(const half8*)&Vts[d * 16 + m][ks * 32 + quad * 8];
                o[d] = __builtin_amdgcn_mfma_f32_16x16x32_f16(af, bf, o[d], 0, 0, 0);
            }
        }
    }
    #pragma unroll
    for (int d = 0; d < 4; ++d)
        #pragma unroll
        for (int r = 0; r < 4; ++r) {
            const int row = q_base + wave * 16 + quad * 4 + r;
            Out[bh_off + (size_t)row * HD + d * 16 + m] = o[d][r] / li[r];
        }
}

extern "C" void kernel_launch(void* const* d_in, const int* in_sizes, int n_in,
                              void* d_out, int out_size, void* d_ws, size_t ws_size,
                              hipStream_t stream) {
    const float* q = (const float*)d_in[0];
    const float* k = (const float*)d_in[1];
    const float* v = (const float*)d_in[2];
    float* out = (float*)d_out;

    const size_t nelem = (size_t)B * N * H * D;           // 4194304
    const size_t need = 2 * nelem * sizeof(_Float16);     // Kf + Vt

    if (ws_size >= need) {
        _Float16* Kf = (_Float16*)d_ws;
        _Float16* Vtr = Kf + nelem;
        prep_kernel<<<dim3(2048 + 1024), 256, 0, stream>>>(k, v, Kf, Vtr);
        fattn16_kernel<<<dim3(N / QT, H, B), 512, 0, stream>>>(q, Kf, Vtr, out);
    } else {
        fattn_fb_kernel<<<dim3(N / 64, H, B), 256, 0, stream>>>(q, k, v, out);
    }
}